// Round 9
// baseline (9271.345 us; speedup 1.0000x reference)
//
#include <hip/hip_runtime.h>
#include <hip/hip_bf16.h>

typedef __attribute__((ext_vector_type(4))) float  fvec4;
typedef __attribute__((ext_vector_type(8))) short  svec8;    // 8 bf16 (4 VGPRs), MFMA A/B frag
typedef __attribute__((ext_vector_type(8))) unsigned short usvec8;
typedef __attribute__((ext_vector_type(4))) unsigned short usvec4;
typedef __attribute__((ext_vector_type(2))) unsigned int   uivec2;
typedef __attribute__((ext_vector_type(4))) unsigned int   uivec4;

#define MFMA16 __builtin_amdgcn_mfma_f32_16x16x32_bf16

static __device__ __forceinline__ unsigned short f2bf(float f) {
    __hip_bfloat16 h = __float2bfloat16(f);
    return __builtin_bit_cast(unsigned short, h);
}
static __device__ __forceinline__ float bf2f(unsigned short u) {
    unsigned int v = ((unsigned int)u) << 16;
    return __builtin_bit_cast(float, v);
}

// ---------------- fp32 -> bf16 convert ----------------
__global__ void cvt_kernel(const float* __restrict__ in, unsigned short* __restrict__ out, int n4) {
    int stride = gridDim.x * blockDim.x;
    for (int i = blockIdx.x * blockDim.x + threadIdx.x; i < n4; i += stride) {
        fvec4 v = ((const fvec4*)in)[i];
        usvec4 u;
        u[0] = f2bf(v[0]); u[1] = f2bf(v[1]); u[2] = f2bf(v[2]); u[3] = f2bf(v[3]);
        ((usvec4*)out)[i] = u;
    }
}

// ---------------- GEMM: out[m][n] = sum_k lhs[m][k] * rhs[n][k], K=N=512 ----------------
// (unchanged since round 1 — verified)
template<bool LHS_F32_PERM, bool OUT_PERM>
__global__ __launch_bounds__(256)
void gemm512(const void* __restrict__ lhsv, const unsigned short* __restrict__ rhs,
             void* __restrict__ outv)
{
    __shared__ __align__(16) unsigned short smA[64 * 72];
    __shared__ __align__(16) unsigned short smB[64 * 72];
    const int tid = threadIdx.x;
    const int m0 = blockIdx.x * 64;
    const int n0 = blockIdx.y * 64;
    const int w = tid >> 6, l = tid & 63;
    const int g = l >> 4, r16 = l & 15;
    const int wm = (w >> 1) * 32, wn = (w & 1) * 32;
    const int ri = tid >> 2;
    const int kseg = (tid & 3) * 16;

    fvec4 acc[2][2] = {};

    for (int k0 = 0; k0 < 512; k0 += 64) {
        if (LHS_F32_PERM) {
            const float* x = (const float*)lhsv;
            int m = m0 + ri;
            size_t base = ((size_t)(m & 15) * 4096 + (size_t)(m >> 4)) * 512 + k0 + kseg;
            usvec8 o0, o1;
            fvec4 v0 = *(const fvec4*)(x + base + 0);
            fvec4 v1 = *(const fvec4*)(x + base + 4);
            fvec4 v2 = *(const fvec4*)(x + base + 8);
            fvec4 v3 = *(const fvec4*)(x + base + 12);
            o0[0]=f2bf(v0[0]); o0[1]=f2bf(v0[1]); o0[2]=f2bf(v0[2]); o0[3]=f2bf(v0[3]);
            o0[4]=f2bf(v1[0]); o0[5]=f2bf(v1[1]); o0[6]=f2bf(v1[2]); o0[7]=f2bf(v1[3]);
            o1[0]=f2bf(v2[0]); o1[1]=f2bf(v2[1]); o1[2]=f2bf(v2[2]); o1[3]=f2bf(v2[3]);
            o1[4]=f2bf(v3[0]); o1[5]=f2bf(v3[1]); o1[6]=f2bf(v3[2]); o1[7]=f2bf(v3[3]);
            *(usvec8*)(smA + ri * 72 + kseg)     = o0;
            *(usvec8*)(smA + ri * 72 + kseg + 8) = o1;
        } else {
            const unsigned short* s = (const unsigned short*)lhsv;
            size_t base = (size_t)(m0 + ri) * 512 + k0 + kseg;
            *(usvec8*)(smA + ri * 72 + kseg)     = *(const usvec8*)(s + base);
            *(usvec8*)(smA + ri * 72 + kseg + 8) = *(const usvec8*)(s + base + 8);
        }
        {
            size_t base = (size_t)(n0 + ri) * 512 + k0 + kseg;
            *(usvec8*)(smB + ri * 72 + kseg)     = *(const usvec8*)(rhs + base);
            *(usvec8*)(smB + ri * 72 + kseg + 8) = *(const usvec8*)(rhs + base + 8);
        }
        __syncthreads();
        #pragma unroll
        for (int kt = 0; kt < 2; ++kt) {
            svec8 a0 = *(const svec8*)(smA + (wm +      r16) * 72 + 32 * kt + 8 * g);
            svec8 a1 = *(const svec8*)(smA + (wm + 16 + r16) * 72 + 32 * kt + 8 * g);
            svec8 b0 = *(const svec8*)(smB + (wn +      r16) * 72 + 32 * kt + 8 * g);
            svec8 b1 = *(const svec8*)(smB + (wn + 16 + r16) * 72 + 32 * kt + 8 * g);
            acc[0][0] = MFMA16(a0, b0, acc[0][0], 0, 0, 0);
            acc[0][1] = MFMA16(a0, b1, acc[0][1], 0, 0, 0);
            acc[1][0] = MFMA16(a1, b0, acc[1][0], 0, 0, 0);
            acc[1][1] = MFMA16(a1, b1, acc[1][1], 0, 0, 0);
        }
        __syncthreads();
    }
    #pragma unroll
    for (int mt = 0; mt < 2; ++mt)
    #pragma unroll
    for (int nt = 0; nt < 2; ++nt)
    #pragma unroll
    for (int r = 0; r < 4; ++r) {
        int m = m0 + wm + 16 * mt + 4 * g + r;
        int n = n0 + wn + 16 * nt + r16;
        float v = acc[mt][nt][r];
        if (OUT_PERM) {
            float* out = (float*)outv;
            out[((size_t)(m & 15) * 4096 + (size_t)(m >> 4)) * 512 + n] = v;
        } else {
            unsigned short* out = (unsigned short*)outv;
            out[(size_t)m * 512 + n] = f2bf(v);
        }
    }
}

// ---------------- recurrence: ONE workgroup, 4 waves, A in AGPR+VGPR+LDS ----------------
// Memory structure = round 7 (all-LDS A, proven absmax 0.03125). Round-9 deltas attack
// the SERIAL VALU clump identified from r5/r7 counters (issue-bound single wave/SIMD):
//   - acc init via MFMA with inline-constant C=0 (KTSTEP0, write-only asm): kills
//     32 v_mov + the s_nop-1 VALU->MFMA-C fence
//   - bq decode reduced 12->4 ops per mt (lo<<16 / lo&0xffff0000) and emitted as 16
//     tiny pieces BETWEEN KTSTEP regions: they issue inside MFMA pipe-drain gaps
//   - epilogue keeps only add/relu/cvt_pk/ds_write
// A-split per wave: mt0..3 -> AGPR ("a" asm), mt4..5 -> VGPR, mt6..7 -> LDS frag-linear.
// Mappings (verified rounds 2-7, absmax 0.03125):
//   A-frag: lane l -> m = l&15, k = 32kt + 8(l>>4) + e
//   B-frag: lane l -> n = l&15 (batch), k = 32kt + 8(l>>4) + e
//   C/D:    lane l -> n = l&15 (batch), m = 4(l>>4) + reg
#define RT 4096

#define LDSB(KT) (*(const svec8*)(stp + ((64 * (KT) + 16 * g) ^ swz)))
#define LDSA(J, KT) (*(const svec8*)(ldsA + (((w * 2 + (J)) * 16 + (KT)) << 9) + l * 8))

#define MFA(ACC, AF, SB)  asm("v_mfma_f32_16x16x32_bf16 %0, %1, %2, %0" : "+v"(ACC) : "a"(AF), "v"(SB))
#define MFV(ACC, AF, SB)  asm("v_mfma_f32_16x16x32_bf16 %0, %1, %2, %0" : "+v"(ACC) : "v"(AF), "v"(SB))
#define MFA0(ACC, AF, SB) asm("v_mfma_f32_16x16x32_bf16 %0, %1, %2, 0"  : "=v"(ACC) : "a"(AF), "v"(SB))
#define MFV0(ACC, AF, SB) asm("v_mfma_f32_16x16x32_bf16 %0, %1, %2, 0"  : "=v"(ACC) : "v"(AF), "v"(SB))

// kt = 0: C = inline constant 0 (defines all 8 accs; no VALU init, no init fence)
#define KTSTEP0() do { \
    sbv[2] = LDSB(2); \
    s6a[2] = LDSA(0, 2); \
    s7a[2] = LDSA(1, 2); \
    svec8 sc = sbv[0]; \
    MFA0(acc[0], af_a[0][0], sc); \
    MFA0(acc[1], af_a[0][1], sc); \
    MFA0(acc[2], af_a[0][2], sc); \
    MFA0(acc[3], af_a[0][3], sc); \
    MFV0(acc[4], af_v[0][0], sc); \
    MFV0(acc[5], af_v[0][1], sc); \
    MFV0(acc[6], s6a[0], sc); \
    MFV0(acc[7], s7a[0], sc); \
    __builtin_amdgcn_sched_barrier(0); \
} while (0)

// body for kt 1..13: prefetch all three LDS streams at distance 2, then 8 MFMAs
#define KTSTEP(KT) do { \
    sbv[((KT) + 2) % 3] = LDSB((KT) + 2); \
    s6a[((KT) + 2) % 3] = LDSA(0, (KT) + 2); \
    s7a[((KT) + 2) % 3] = LDSA(1, (KT) + 2); \
    svec8 sc = sbv[(KT) % 3]; \
    MFA(acc[0], af_a[KT][0], sc); \
    MFA(acc[1], af_a[KT][1], sc); \
    MFA(acc[2], af_a[KT][2], sc); \
    MFA(acc[3], af_a[KT][3], sc); \
    MFV(acc[4], af_v[KT][0], sc); \
    MFV(acc[5], af_v[KT][1], sc); \
    MFV(acc[6], s6a[(KT) % 3], sc); \
    MFV(acc[7], s7a[(KT) % 3], sc); \
    __builtin_amdgcn_sched_barrier(0); \
} while (0)

// tail body for kt 14,15: no prefetch
#define KTSTEPNP(KT) do { \
    svec8 sc = sbv[(KT) % 3]; \
    MFA(acc[0], af_a[KT][0], sc); \
    MFA(acc[1], af_a[KT][1], sc); \
    MFA(acc[2], af_a[KT][2], sc); \
    MFA(acc[3], af_a[KT][3], sc); \
    MFV(acc[4], af_v[KT][0], sc); \
    MFV(acc[5], af_v[KT][1], sc); \
    MFV(acc[6], s6a[(KT) % 3], sc); \
    MFV(acc[7], s7a[(KT) % 3], sc); \
    __builtin_amdgcn_sched_barrier(0); \
} while (0)

// decode one u32 (2 bf16) of bq[MT] into f32: issues in MFMA pipe-drain gaps
#define DEC(MT, H) do { \
    unsigned int _wd = (unsigned int)(bq[MT] >> (32 * (H))); \
    bqf[MT][2 * (H)]     = __builtin_bit_cast(float, _wd << 16); \
    bqf[MT][2 * (H) + 1] = __builtin_bit_cast(float, _wd & 0xffff0000u); \
} while (0)

__global__ __launch_bounds__(256, 1)
void recur1cu_kernel(const unsigned short* __restrict__ Abf,   // [512][512] bf16, A[n][k]
                     const unsigned short* __restrict__ bx,    // [65536][512] bf16, row = t*16+b
                     unsigned short* __restrict__ states)      // [65536][512] bf16, row = t*16+b
{
    __shared__ __align__(16) unsigned short st[2][16 * 512];         // 32 KB state dbuf, row=b, XOR-swizzled
    __shared__ __align__(16) unsigned short ldsA[4 * 2 * 16 * 512];  // 128 KB: [w][mt-6][kt][frag 1KB]
    const int tid = threadIdx.x;
    const int w = tid >> 6, l = tid & 63;
    const int g = l >> 4, r16 = l & 15;
    const int nbase = w * 128;
    const int swz = (r16 & 7) << 4;

    // ---- stage A mt=6,7 into LDS, fragment-linear ----
    #pragma unroll
    for (int j = 0; j < 2; ++j)
        #pragma unroll
        for (int kt = 0; kt < 16; ++kt) {
            usvec8 v = *(const usvec8*)(Abf + (size_t)(nbase + 16 * (6 + j) + r16) * 512
                                        + 32 * kt + 8 * g);
            *(usvec8*)(ldsA + (((w * 2 + j) * 16 + kt) << 9) + l * 8) = v;
        }

    // ---- preload A mt=0..3 (AGPR-destined, used only via "a" asm operands) ----
    svec8 af_a[16][4];
    #pragma unroll
    for (int kt = 0; kt < 16; ++kt)
        #pragma unroll
        for (int mt = 0; mt < 4; ++mt)
            af_a[kt][mt] = *(const svec8*)(Abf + (size_t)(nbase + 16 * mt + r16) * 512
                                           + 32 * kt + 8 * g);

    // ---- preload A mt=4,5 into arch VGPRs (128 regs) ----
    svec8 af_v[16][2];
    #pragma unroll
    for (int kt = 0; kt < 16; ++kt)
        #pragma unroll
        for (int j = 0; j < 2; ++j)
            af_v[kt][j] = *(const svec8*)(Abf + (size_t)(nbase + 16 * (4 + j) + r16) * 512
                                          + 32 * kt + 8 * g);

    // ---- t = 0: state0 = relu(bx[0]) -> st[0] ----
    {
        const unsigned short* bp = bx + (size_t)r16 * 512 + nbase + 4 * g;
        char* stq = (char*)&st[0][0] + r16 * 1024;
        #pragma unroll
        for (int mt = 0; mt < 8; ++mt) {
            unsigned long long u = *(const unsigned long long*)(bp + 16 * mt);
            float f0 = fmaxf(bf2f((unsigned short)( u        & 0xffffu)), 0.0f);
            float f1 = fmaxf(bf2f((unsigned short)((u >> 16) & 0xffffu)), 0.0f);
            float f2 = fmaxf(bf2f((unsigned short)((u >> 32) & 0xffffu)), 0.0f);
            float f3 = fmaxf(bf2f((unsigned short)((u >> 48) & 0xffffu)), 0.0f);
            unsigned int plo, phi;
            asm("v_cvt_pk_bf16_f32 %0, %1, %2" : "=v"(plo) : "v"(f0), "v"(f1));
            asm("v_cvt_pk_bf16_f32 %0, %1, %2" : "=v"(phi) : "v"(f2), "v"(f3));
            uivec2 ov; ov[0] = plo; ov[1] = phi;
            *(uivec2*)(stq + ((2 * (nbase + 16 * mt + 4 * g)) ^ swz)) = ov;
        }
    }
    __syncthreads();

    // export lane mapping: wave w exports state rows 4w..4w+3 (coalesced 16B chunks)
    const int erow = 4 * w + (l >> 4);
    const int eswz = (erow & 7) << 4;
    const int ecol = (l & 15) * 16;

    #pragma unroll 1
    for (int t = 1; t < RT; ++t) {
        const char* stbase_p = (const char*)&st[(t - 1) & 1][0];

        // A) coalesced export of state_{t-1} from st[p]; store drain overlaps MFMA region
        {
            const char* sp = stbase_p + erow * 1024;
            char* gp = (char*)states + ((size_t)(t - 1) * 16 + erow) * 1024 + ecol;
            #pragma unroll
            for (int jj = 0; jj < 4; ++jj) {
                uivec4 v = *(const uivec4*)(sp + ((ecol + 256 * jj) ^ eswz));
                *(uivec4*)(gp + 256 * jj) = v;
            }
        }

        // B) bx[t] loads (decoded in gaps; HBM latency hidden under MFMA region)
        unsigned long long bq[8];
        {
            const unsigned short* bp = bx + ((size_t)t * 16 + r16) * 512 + nbase + 4 * g;
            #pragma unroll
            for (int mt = 0; mt < 8; ++mt)
                bq[mt] = *(const unsigned long long*)(bp + 16 * mt);
        }

        // C) MFMA region: reads st[p]; kt0 defines accs (C=0 literal); DEC pieces
        //    between regions issue inside MFMA pipe-drain gaps
        fvec4 acc[8];
        float bqf[8][4];
        const char* stp = stbase_p + r16 * 1024;
        svec8 sbv[3], s6a[3], s7a[3];
        sbv[0] = LDSB(0); sbv[1] = LDSB(1);
        s6a[0] = LDSA(0, 0); s6a[1] = LDSA(0, 1);
        s7a[0] = LDSA(1, 0); s7a[1] = LDSA(1, 1);
        KTSTEP0();    DEC(0, 0);
        KTSTEP(1);    DEC(0, 1);
        KTSTEP(2);    DEC(1, 0);
        KTSTEP(3);    DEC(1, 1);
        KTSTEP(4);    DEC(2, 0);
        KTSTEP(5);    DEC(2, 1);
        KTSTEP(6);    DEC(3, 0);
        KTSTEP(7);    DEC(3, 1);
        KTSTEP(8);    DEC(4, 0);
        KTSTEP(9);    DEC(4, 1);
        KTSTEP(10);   DEC(5, 0);
        KTSTEP(11);   DEC(5, 1);
        KTSTEP(12);   DEC(6, 0);
        KTSTEP(13);   DEC(6, 1);
        KTSTEPNP(14); DEC(7, 0);
        KTSTEPNP(15); DEC(7, 1);

        // MFMA-write -> VALU-read hazard fence
        asm volatile("s_nop 7\n\ts_nop 7"
                     : "+v"(acc[0]), "+v"(acc[1]), "+v"(acc[2]), "+v"(acc[3]),
                       "+v"(acc[4]), "+v"(acc[5]), "+v"(acc[6]), "+v"(acc[7]));

        // D) epilogue: + bxf, relu, cvt_pk pack; write st[q] (swizzled)
        {
            char* stq = (char*)&st[t & 1][0] + r16 * 1024;
            #pragma unroll
            for (int mt = 0; mt < 8; ++mt) {
                float f0 = fmaxf(acc[mt][0] + bqf[mt][0], 0.0f);
                float f1 = fmaxf(acc[mt][1] + bqf[mt][1], 0.0f);
                float f2 = fmaxf(acc[mt][2] + bqf[mt][2], 0.0f);
                float f3 = fmaxf(acc[mt][3] + bqf[mt][3], 0.0f);
                unsigned int plo, phi;
                asm("v_cvt_pk_bf16_f32 %0, %1, %2" : "=v"(plo) : "v"(f0), "v"(f1));
                asm("v_cvt_pk_bf16_f32 %0, %1, %2" : "=v"(phi) : "v"(f2), "v"(f3));
                uivec2 ov; ov[0] = plo; ov[1] = phi;
                *(uivec2*)(stq + ((2 * (nbase + 16 * mt + 4 * g)) ^ swz)) = ov;
            }
        }

        __syncthreads();   // single barrier: st[q] complete; st[p] free for overwrite next iter
    }

    // ---- final export: state_{RT-1} from st[(RT-1)&1] ----
    {
        const char* sp = (const char*)&st[(RT - 1) & 1][0] + erow * 1024;
        char* gp = (char*)states + ((size_t)(RT - 1) * 16 + erow) * 1024 + ecol;
        #pragma unroll
        for (int jj = 0; jj < 4; ++jj) {
            uivec4 v = *(const uivec4*)(sp + ((ecol + 256 * jj) ^ eswz));
            *(uivec4*)(gp + 256 * jj) = v;
        }
    }
}

extern "C" void kernel_launch(void* const* d_in, const int* in_sizes, int n_in,
                              void* d_out, int out_size, void* d_ws, size_t ws_size,
                              hipStream_t stream) {
    const float* x = (const float*)d_in[0];   // [16][4096][512]
    const float* A = (const float*)d_in[1];   // [512][512]
    const float* B = (const float*)d_in[2];   // [512][512]
    const float* C = (const float*)d_in[3];   // [512][512]
    float* out = (float*)d_out;               // [16][4096][512]

    char* ws = (char*)d_ws;
    unsigned short* Abf = (unsigned short*)(ws + 0);                          // 512KB
    unsigned short* Bbf = (unsigned short*)(ws + (size_t)(1 << 19));          // 512KB
    unsigned short* Cbf = (unsigned short*)(ws + (size_t)(2 << 19));          // 512KB
    unsigned short* bx  = (unsigned short*)(ws + (size_t)(4 << 19));          // 64MB: [65536][512] bf16
    unsigned short* states = (unsigned short*)(ws + (size_t)(4 << 19) + ((size_t)1 << 26)); // 64MB

    cvt_kernel<<<64, 256, 0, stream>>>(A, Abf, 512 * 512 / 4);
    cvt_kernel<<<64, 256, 0, stream>>>(B, Bbf, 512 * 512 / 4);
    cvt_kernel<<<64, 256, 0, stream>>>(C, Cbf, 512 * 512 / 4);

    dim3 grid(1024, 8);
    // bx[t*16+b][n] = sum_d x[b][t][d] * B[n][d]
    gemm512<true, false><<<grid, 256, 0, stream>>>((const void*)x, Bbf, (void*)bx);
    // sequential recurrence on one CU, states[t*16+b][n]
    recur1cu_kernel<<<1, 256, 0, stream>>>(Abf, bx, states);
    // y[b][t][j] = sum_n states[t*16+b][n] * C[j][n]
    gemm512<false, true><<<grid, 256, 0, stream>>>((const void*)states, Cbf, (void*)out);
}

// Round 10
// 7450.293 us; speedup vs baseline: 1.2444x; 1.2444x over previous
//
#include <hip/hip_runtime.h>
#include <hip/hip_bf16.h>

typedef __attribute__((ext_vector_type(4))) float  fvec4;
typedef __attribute__((ext_vector_type(8))) short  svec8;    // 8 bf16 (4 VGPRs), MFMA A/B frag
typedef __attribute__((ext_vector_type(8))) unsigned short usvec8;
typedef __attribute__((ext_vector_type(4))) unsigned short usvec4;
typedef __attribute__((ext_vector_type(2))) unsigned int   uivec2;
typedef __attribute__((ext_vector_type(4))) unsigned int   uivec4;

#define MFMA16 __builtin_amdgcn_mfma_f32_16x16x32_bf16

static __device__ __forceinline__ unsigned short f2bf(float f) {
    __hip_bfloat16 h = __float2bfloat16(f);
    return __builtin_bit_cast(unsigned short, h);
}
static __device__ __forceinline__ float bf2f(unsigned short u) {
    unsigned int v = ((unsigned int)u) << 16;
    return __builtin_bit_cast(float, v);
}

// ---------------- fp32 -> bf16 convert ----------------
__global__ void cvt_kernel(const float* __restrict__ in, unsigned short* __restrict__ out, int n4) {
    int stride = gridDim.x * blockDim.x;
    for (int i = blockIdx.x * blockDim.x + threadIdx.x; i < n4; i += stride) {
        fvec4 v = ((const fvec4*)in)[i];
        usvec4 u;
        u[0] = f2bf(v[0]); u[1] = f2bf(v[1]); u[2] = f2bf(v[2]); u[3] = f2bf(v[3]);
        ((usvec4*)out)[i] = u;
    }
}

// ---------------- GEMM: out[m][n] = sum_k lhs[m][k] * rhs[n][k], K=N=512 ----------------
// (unchanged since round 1 — verified)
template<bool LHS_F32_PERM, bool OUT_PERM>
__global__ __launch_bounds__(256)
void gemm512(const void* __restrict__ lhsv, const unsigned short* __restrict__ rhs,
             void* __restrict__ outv)
{
    __shared__ __align__(16) unsigned short smA[64 * 72];
    __shared__ __align__(16) unsigned short smB[64 * 72];
    const int tid = threadIdx.x;
    const int m0 = blockIdx.x * 64;
    const int n0 = blockIdx.y * 64;
    const int w = tid >> 6, l = tid & 63;
    const int g = l >> 4, r16 = l & 15;
    const int wm = (w >> 1) * 32, wn = (w & 1) * 32;
    const int ri = tid >> 2;
    const int kseg = (tid & 3) * 16;

    fvec4 acc[2][2] = {};

    for (int k0 = 0; k0 < 512; k0 += 64) {
        if (LHS_F32_PERM) {
            const float* x = (const float*)lhsv;
            int m = m0 + ri;
            size_t base = ((size_t)(m & 15) * 4096 + (size_t)(m >> 4)) * 512 + k0 + kseg;
            usvec8 o0, o1;
            fvec4 v0 = *(const fvec4*)(x + base + 0);
            fvec4 v1 = *(const fvec4*)(x + base + 4);
            fvec4 v2 = *(const fvec4*)(x + base + 8);
            fvec4 v3 = *(const fvec4*)(x + base + 12);
            o0[0]=f2bf(v0[0]); o0[1]=f2bf(v0[1]); o0[2]=f2bf(v0[2]); o0[3]=f2bf(v0[3]);
            o0[4]=f2bf(v1[0]); o0[5]=f2bf(v1[1]); o0[6]=f2bf(v1[2]); o0[7]=f2bf(v1[3]);
            o1[0]=f2bf(v2[0]); o1[1]=f2bf(v2[1]); o1[2]=f2bf(v2[2]); o1[3]=f2bf(v2[3]);
            o1[4]=f2bf(v3[0]); o1[5]=f2bf(v3[1]); o1[6]=f2bf(v3[2]); o1[7]=f2bf(v3[3]);
            *(usvec8*)(smA + ri * 72 + kseg)     = o0;
            *(usvec8*)(smA + ri * 72 + kseg + 8) = o1;
        } else {
            const unsigned short* s = (const unsigned short*)lhsv;
            size_t base = (size_t)(m0 + ri) * 512 + k0 + kseg;
            *(usvec8*)(smA + ri * 72 + kseg)     = *(const usvec8*)(s + base);
            *(usvec8*)(smA + ri * 72 + kseg + 8) = *(const usvec8*)(s + base + 8);
        }
        {
            size_t base = (size_t)(n0 + ri) * 512 + k0 + kseg;
            *(usvec8*)(smB + ri * 72 + kseg)     = *(const usvec8*)(rhs + base);
            *(usvec8*)(smB + ri * 72 + kseg + 8) = *(const usvec8*)(rhs + base + 8);
        }
        __syncthreads();
        #pragma unroll
        for (int kt = 0; kt < 2; ++kt) {
            svec8 a0 = *(const svec8*)(smA + (wm +      r16) * 72 + 32 * kt + 8 * g);
            svec8 a1 = *(const svec8*)(smA + (wm + 16 + r16) * 72 + 32 * kt + 8 * g);
            svec8 b0 = *(const svec8*)(smB + (wn +      r16) * 72 + 32 * kt + 8 * g);
            svec8 b1 = *(const svec8*)(smB + (wn + 16 + r16) * 72 + 32 * kt + 8 * g);
            acc[0][0] = MFMA16(a0, b0, acc[0][0], 0, 0, 0);
            acc[0][1] = MFMA16(a0, b1, acc[0][1], 0, 0, 0);
            acc[1][0] = MFMA16(a1, b0, acc[1][0], 0, 0, 0);
            acc[1][1] = MFMA16(a1, b1, acc[1][1], 0, 0, 0);
        }
        __syncthreads();
    }
    #pragma unroll
    for (int mt = 0; mt < 2; ++mt)
    #pragma unroll
    for (int nt = 0; nt < 2; ++nt)
    #pragma unroll
    for (int r = 0; r < 4; ++r) {
        int m = m0 + wm + 16 * mt + 4 * g + r;
        int n = n0 + wn + 16 * nt + r16;
        float v = acc[mt][nt][r];
        if (OUT_PERM) {
            float* out = (float*)outv;
            out[((size_t)(m & 15) * 4096 + (size_t)(m >> 4)) * 512 + n] = v;
        } else {
            unsigned short* out = (unsigned short*)outv;
            out[(size_t)m * 512 + n] = f2bf(v);
        }
    }
}

// ---------------- recurrence: ONE workgroup, 4 waves, rotated-K software pipeline -----------
// Wave w owns n_out [128w,128w+128). Per-wave kt ITERATION ORDER is rotated:
//   i -> ktphys kp(i) = (4w+4+i)&15, so i=12..15 are the wave's OWN kts (4w..4w+3),
//   i.e. the state columns this wave itself writes. Rotation is applied at fragment
//   LOAD time (af_a/af_v/ldsA stored in i-order), so all register arrays stay
//   statically indexed; only the state ds_read offsets (kb[i]) are runtime-uniform.
// Step: barrier -> export/bq -> 12 foreign kt (96 MFMAs, reads st[p]) -> fence ->
//   interleaved { EP(mt-pair) writes st[q] own cols  ||  own-kt MFMAs for t+1
//   (MFA0 C=0 re-init, reads st[q] own cols — no peer dependency, no barrier) } -> barrier.
// 32 of 128 MFMAs hide in the epilogue shadow; acc regs are recycled mt-by-mt.
// A-split per wave: mt0..3 -> AGPR ("a"), mt4..5 -> VGPR, mt6..7 -> LDS frag-linear (i-order).
// bq decoded INSIDE EP (transient — round-9's bqf live-range regression avoided).
// Mappings (verified rounds 2-9, absmax 0.03125):
//   A-frag: lane l -> m = l&15, k = 32kt + 8(l>>4) + e
//   B-frag: lane l -> n = l&15 (batch), k = 32kt + 8(l>>4) + e
//   C/D:    lane l -> n = l&15 (batch), m = 4(l>>4) + reg
#define RT 4096

#define LDSBP(I) (*(const svec8*)(stp + ((kb[I] + 16 * g) ^ swz)))
#define LDSBQ(P, I) (*(const svec8*)((P) + ((kb[I] + 16 * g) ^ swz)))
#define LDSA(J, I) (*(const svec8*)(ldsA + (((w * 2 + (J)) * 16 + (I)) << 9) + l * 8))

#define MFA(ACC, AF, SB)  asm("v_mfma_f32_16x16x32_bf16 %0, %1, %2, %0" : "+v"(ACC) : "a"(AF), "v"(SB))
#define MFV(ACC, AF, SB)  asm("v_mfma_f32_16x16x32_bf16 %0, %1, %2, %0" : "+v"(ACC) : "v"(AF), "v"(SB))
#define MFA0(ACC, AF, SB) asm("v_mfma_f32_16x16x32_bf16 %0, %1, %2, 0"  : "=v"(ACC) : "a"(AF), "v"(SB))
#define MFV0(ACC, AF, SB) asm("v_mfma_f32_16x16x32_bf16 %0, %1, %2, 0"  : "=v"(ACC) : "v"(AF), "v"(SB))
#define SBAR __builtin_amdgcn_sched_barrier(0)

// foreign body i=0..9: prefetch all three LDS streams at distance 2, 8 MFMAs, "+v" acc
#define FSTEP(I) do { \
    sbv[((I) + 2) % 3] = LDSBP((I) + 2); \
    s6a[((I) + 2) % 3] = LDSA(0, (I) + 2); \
    s7a[((I) + 2) % 3] = LDSA(1, (I) + 2); \
    svec8 sc = sbv[(I) % 3]; \
    MFA(acc[0], af_a[I][0], sc); \
    MFA(acc[1], af_a[I][1], sc); \
    MFA(acc[2], af_a[I][2], sc); \
    MFA(acc[3], af_a[I][3], sc); \
    MFV(acc[4], af_v[I][0], sc); \
    MFV(acc[5], af_v[I][1], sc); \
    MFV(acc[6], s6a[(I) % 3], sc); \
    MFV(acc[7], s7a[(I) % 3], sc); \
    SBAR; \
} while (0)

// foreign tail i=10,11: no prefetch
#define FSTEPNP(I) do { \
    svec8 sc = sbv[(I) % 3]; \
    MFA(acc[0], af_a[I][0], sc); \
    MFA(acc[1], af_a[I][1], sc); \
    MFA(acc[2], af_a[I][2], sc); \
    MFA(acc[3], af_a[I][3], sc); \
    MFV(acc[4], af_v[I][0], sc); \
    MFV(acc[5], af_v[I][1], sc); \
    MFV(acc[6], s6a[(I) % 3], sc); \
    MFV(acc[7], s7a[(I) % 3], sc); \
    SBAR; \
} while (0)

// epilogue for one mt: +bx (decode inline, transient), relu, cvt_pk, ds_write st[q]
#define EP(MT) do { \
    unsigned long long _u = bq[MT]; \
    float _f0 = fmaxf(acc[MT][0] + bf2f((unsigned short)( _u        & 0xffffu)), 0.0f); \
    float _f1 = fmaxf(acc[MT][1] + bf2f((unsigned short)((_u >> 16) & 0xffffu)), 0.0f); \
    float _f2 = fmaxf(acc[MT][2] + bf2f((unsigned short)((_u >> 32) & 0xffffu)), 0.0f); \
    float _f3 = fmaxf(acc[MT][3] + bf2f((unsigned short)((_u >> 48) & 0xffffu)), 0.0f); \
    unsigned int _plo, _phi; \
    asm("v_cvt_pk_bf16_f32 %0, %1, %2" : "=v"(_plo) : "v"(_f0), "v"(_f1)); \
    asm("v_cvt_pk_bf16_f32 %0, %1, %2" : "=v"(_phi) : "v"(_f2), "v"(_f3)); \
    uivec2 _ov; _ov[0] = _plo; _ov[1] = _phi; \
    *(uivec2*)(stq + ((2 * (nbase + 16 * (MT) + 4 * g)) ^ swz)) = _ov; \
} while (0)

__global__ __launch_bounds__(256, 1)
void recur1cu_kernel(const unsigned short* __restrict__ Abf,   // [512][512] bf16, A[n][k]
                     const unsigned short* __restrict__ bx,    // [65536][512] bf16, row = t*16+b
                     unsigned short* __restrict__ states)      // [65536][512] bf16, row = t*16+b
{
    __shared__ __align__(16) unsigned short st[2][16 * 512];         // 32 KB state dbuf, XOR-swizzled
    __shared__ __align__(16) unsigned short ldsA[4 * 2 * 16 * 512];  // 128 KB: [w][mt-6][i][frag 1KB]
    const int tid = threadIdx.x;
    const int w = tid >> 6, l = tid & 63;
    const int g = l >> 4, r16 = l & 15;
    const int nbase = w * 128;
    const int swz = (r16 & 7) << 4;

    // rotated kt order: i -> kp[i]; kb[i] = state byte offset of that kt
    int kp[16], kb[16];
    #pragma unroll
    for (int i = 0; i < 16; ++i) { kp[i] = (4 * w + 4 + i) & 15; kb[i] = kp[i] * 64; }

    // ---- stage A mt=6,7 into LDS, fragment-linear in i-order ----
    #pragma unroll
    for (int j = 0; j < 2; ++j)
        #pragma unroll
        for (int i = 0; i < 16; ++i) {
            usvec8 v = *(const usvec8*)(Abf + (size_t)(nbase + 16 * (6 + j) + r16) * 512
                                        + 32 * kp[i] + 8 * g);
            *(usvec8*)(ldsA + (((w * 2 + j) * 16 + i) << 9) + l * 8) = v;
        }

    // ---- preload A mt=0..3 (AGPR-destined) and mt=4,5 (VGPR), i-order ----
    svec8 af_a[16][4];
    #pragma unroll
    for (int i = 0; i < 16; ++i)
        #pragma unroll
        for (int mt = 0; mt < 4; ++mt)
            af_a[i][mt] = *(const svec8*)(Abf + (size_t)(nbase + 16 * mt + r16) * 512
                                          + 32 * kp[i] + 8 * g);
    svec8 af_v[16][2];
    #pragma unroll
    for (int i = 0; i < 16; ++i)
        #pragma unroll
        for (int j = 0; j < 2; ++j)
            af_v[i][j] = *(const svec8*)(Abf + (size_t)(nbase + 16 * (4 + j) + r16) * 512
                                         + 32 * kp[i] + 8 * g);

    // ---- t = 0: state0 = relu(bx[0]) -> st[0] own cols ----
    {
        const unsigned short* bp = bx + (size_t)r16 * 512 + nbase + 4 * g;
        char* st0 = (char*)&st[0][0] + r16 * 1024;
        #pragma unroll
        for (int mt = 0; mt < 8; ++mt) {
            unsigned long long u = *(const unsigned long long*)(bp + 16 * mt);
            float f0 = fmaxf(bf2f((unsigned short)( u        & 0xffffu)), 0.0f);
            float f1 = fmaxf(bf2f((unsigned short)((u >> 16) & 0xffffu)), 0.0f);
            float f2 = fmaxf(bf2f((unsigned short)((u >> 32) & 0xffffu)), 0.0f);
            float f3 = fmaxf(bf2f((unsigned short)((u >> 48) & 0xffffu)), 0.0f);
            unsigned int plo, phi;
            asm("v_cvt_pk_bf16_f32 %0, %1, %2" : "=v"(plo) : "v"(f0), "v"(f1));
            asm("v_cvt_pk_bf16_f32 %0, %1, %2" : "=v"(phi) : "v"(f2), "v"(f3));
            uivec2 ov; ov[0] = plo; ov[1] = phi;
            *(uivec2*)(st0 + ((2 * (nbase + 16 * mt + 4 * g)) ^ swz)) = ov;
        }
    }

    fvec4 acc[8];   // loop-carried: holds own-kt partial of the NEXT step at loop entry

    // ---- prologue tail: acc = own-kt partial for t=1, from own-written st[0] cols ----
    {
        const char* sq = (const char*)&st[0][0] + r16 * 1024;
        svec8 sb12 = LDSBQ(sq, 12), sb13 = LDSBQ(sq, 13);
        svec8 sb14 = LDSBQ(sq, 14), sb15 = LDSBQ(sq, 15);
        svec8 t6a = LDSA(0, 12), t6b = LDSA(0, 13), t6c = LDSA(0, 14), t6d = LDSA(0, 15);
        svec8 t7a = LDSA(1, 12), t7b = LDSA(1, 13), t7c = LDSA(1, 14), t7d = LDSA(1, 15);
        MFA0(acc[0], af_a[12][0], sb12);  MFA0(acc[1], af_a[12][1], sb12);
        MFA0(acc[2], af_a[12][2], sb12);  MFA0(acc[3], af_a[12][3], sb12);
        MFV0(acc[4], af_v[12][0], sb12);  MFV0(acc[5], af_v[12][1], sb12);
        MFV0(acc[6], t6a, sb12);          MFV0(acc[7], t7a, sb12);
        MFA(acc[0], af_a[13][0], sb13);   MFA(acc[1], af_a[13][1], sb13);
        MFA(acc[2], af_a[13][2], sb13);   MFA(acc[3], af_a[13][3], sb13);
        MFV(acc[4], af_v[13][0], sb13);   MFV(acc[5], af_v[13][1], sb13);
        MFV(acc[6], t6b, sb13);           MFV(acc[7], t7b, sb13);
        MFA(acc[0], af_a[14][0], sb14);   MFA(acc[1], af_a[14][1], sb14);
        MFA(acc[2], af_a[14][2], sb14);   MFA(acc[3], af_a[14][3], sb14);
        MFV(acc[4], af_v[14][0], sb14);   MFV(acc[5], af_v[14][1], sb14);
        MFV(acc[6], t6c, sb14);           MFV(acc[7], t7c, sb14);
        MFA(acc[0], af_a[15][0], sb15);   MFA(acc[1], af_a[15][1], sb15);
        MFA(acc[2], af_a[15][2], sb15);   MFA(acc[3], af_a[15][3], sb15);
        MFV(acc[4], af_v[15][0], sb15);   MFV(acc[5], af_v[15][1], sb15);
        MFV(acc[6], t6d, sb15);           MFV(acc[7], t7d, sb15);
    }
    __syncthreads();   // st[0] complete (all waves) before foreign reads

    // export lane mapping: wave w exports state rows 4w..4w+3 (coalesced 16B chunks)
    const int erow = 4 * w + (l >> 4);
    const int eswz = (erow & 7) << 4;
    const int ecol = (l & 15) * 16;

    #pragma unroll 1
    for (int t = 1; t < RT; ++t) {
        const char* stbase_p = (const char*)&st[(t - 1) & 1][0];
        char* stq = (char*)&st[t & 1][0] + r16 * 1024;

        // A) coalesced export of state_{t-1}; store drain overlaps MFMA region
        {
            const char* sp = stbase_p + erow * 1024;
            char* gp = (char*)states + ((size_t)(t - 1) * 16 + erow) * 1024 + ecol;
            #pragma unroll
            for (int jj = 0; jj < 4; ++jj) {
                uivec4 v = *(const uivec4*)(sp + ((ecol + 256 * jj) ^ eswz));
                *(uivec4*)(gp + 256 * jj) = v;
            }
        }

        // B) bx[t] loads (decoded inside EP; latency hidden under foreign MFMAs)
        unsigned long long bq[8];
        {
            const unsigned short* bp = bx + ((size_t)t * 16 + r16) * 512 + nbase + 4 * g;
            #pragma unroll
            for (int mt = 0; mt < 8; ++mt)
                bq[mt] = *(const unsigned long long*)(bp + 16 * mt);
        }

        // C) foreign MFMA region: 12 rotated kts, reads st[p], accumulates onto
        //    the own-kt partial carried in from the previous iteration's tail
        const char* stp = stbase_p + r16 * 1024;
        svec8 sbv[3], s6a[3], s7a[3];
        sbv[0] = LDSBP(0); sbv[1] = LDSBP(1);
        s6a[0] = LDSA(0, 0); s6a[1] = LDSA(0, 1);
        s7a[0] = LDSA(1, 0); s7a[1] = LDSA(1, 1);
        FSTEP(0); FSTEP(1); FSTEP(2); FSTEP(3); FSTEP(4);
        FSTEP(5); FSTEP(6); FSTEP(7); FSTEP(8); FSTEP(9);
        FSTEPNP(10); FSTEPNP(11);

        // MFMA-write -> VALU-read hazard fence
        asm volatile("s_nop 7\n\ts_nop 7"
                     : "+v"(acc[0]), "+v"(acc[1]), "+v"(acc[2]), "+v"(acc[3]),
                       "+v"(acc[4]), "+v"(acc[5]), "+v"(acc[6]), "+v"(acc[7]));

        // D) interleaved epilogue + own-kt tail for t+1 (reads/writes st[q] own cols only)
        // G1
        EP(0); EP(1);
        svec8 sb12 = LDSBQ(stq, 12);
        MFA0(acc[0], af_a[12][0], sb12);
        MFA0(acc[1], af_a[12][1], sb12);
        SBAR;
        // G2
        EP(2); EP(3);
        svec8 sb13 = LDSBQ(stq, 13);
        MFA0(acc[2], af_a[12][2], sb12);
        MFA0(acc[3], af_a[12][3], sb12);
        MFA(acc[0], af_a[13][0], sb13);
        MFA(acc[1], af_a[13][1], sb13);
        MFA(acc[2], af_a[13][2], sb13);
        MFA(acc[3], af_a[13][3], sb13);
        SBAR;
        // G3
        EP(4); EP(5);
        svec8 sb14 = LDSBQ(stq, 14);
        MFV0(acc[4], af_v[12][0], sb12);
        MFV0(acc[5], af_v[12][1], sb12);
        MFV(acc[4], af_v[13][0], sb13);
        MFV(acc[5], af_v[13][1], sb13);
        MFA(acc[0], af_a[14][0], sb14);
        MFA(acc[1], af_a[14][1], sb14);
        MFA(acc[2], af_a[14][2], sb14);
        MFA(acc[3], af_a[14][3], sb14);
        SBAR;
        // G4
        EP(6); EP(7);
        svec8 sb15 = LDSBQ(stq, 15);
        svec8 t6a = LDSA(0, 12), t6b = LDSA(0, 13), t6c = LDSA(0, 14), t6d = LDSA(0, 15);
        svec8 t7a = LDSA(1, 12), t7b = LDSA(1, 13), t7c = LDSA(1, 14), t7d = LDSA(1, 15);
        MFA(acc[0], af_a[15][0], sb15);
        MFA(acc[1], af_a[15][1], sb15);
        MFA(acc[2], af_a[15][2], sb15);
        MFA(acc[3], af_a[15][3], sb15);
        MFV(acc[4], af_v[14][0], sb14);
        MFV(acc[5], af_v[14][1], sb14);
        MFV(acc[4], af_v[15][0], sb15);
        MFV(acc[5], af_v[15][1], sb15);
        MFV0(acc[6], t6a, sb12);
        MFV0(acc[7], t7a, sb12);
        MFV(acc[6], t6b, sb13);
        MFV(acc[7], t7b, sb13);
        MFV(acc[6], t6c, sb14);
        MFV(acc[7], t7c, sb14);
        MFV(acc[6], t6d, sb15);
        MFV(acc[7], t7d, sb15);
        SBAR;

        __syncthreads();   // st[q] complete for all waves; st[p] free next iteration
    }

    // ---- final export: state_{RT-1} from st[(RT-1)&1] ----
    {
        const char* sp = (const char*)&st[(RT - 1) & 1][0] + erow * 1024;
        char* gp = (char*)states + ((size_t)(RT - 1) * 16 + erow) * 1024 + ecol;
        #pragma unroll
        for (int jj = 0; jj < 4; ++jj) {
            uivec4 v = *(const uivec4*)(sp + ((ecol + 256 * jj) ^ eswz));
            *(uivec4*)(gp + 256 * jj) = v;
        }
    }
}

extern "C" void kernel_launch(void* const* d_in, const int* in_sizes, int n_in,
                              void* d_out, int out_size, void* d_ws, size_t ws_size,
                              hipStream_t stream) {
    const float* x = (const float*)d_in[0];   // [16][4096][512]
    const float* A = (const float*)d_in[1];   // [512][512]
    const float* B = (const float*)d_in[2];   // [512][512]
    const float* C = (const float*)d_in[3];   // [512][512]
    float* out = (float*)d_out;               // [16][4096][512]

    char* ws = (char*)d_ws;
    unsigned short* Abf = (unsigned short*)(ws + 0);                          // 512KB
    unsigned short* Bbf = (unsigned short*)(ws + (size_t)(1 << 19));          // 512KB
    unsigned short* Cbf = (unsigned short*)(ws + (size_t)(2 << 19));          // 512KB
    unsigned short* bx  = (unsigned short*)(ws + (size_t)(4 << 19));          // 64MB: [65536][512] bf16
    unsigned short* states = (unsigned short*)(ws + (size_t)(4 << 19) + ((size_t)1 << 26)); // 64MB

    cvt_kernel<<<64, 256, 0, stream>>>(A, Abf, 512 * 512 / 4);
    cvt_kernel<<<64, 256, 0, stream>>>(B, Bbf, 512 * 512 / 4);
    cvt_kernel<<<64, 256, 0, stream>>>(C, Cbf, 512 * 512 / 4);

    dim3 grid(1024, 8);
    // bx[t*16+b][n] = sum_d x[b][t][d] * B[n][d]
    gemm512<true, false><<<grid, 256, 0, stream>>>((const void*)x, Bbf, (void*)bx);
    // sequential recurrence on one CU, states[t*16+b][n]
    recur1cu_kernel<<<1, 256, 0, stream>>>(Abf, bx, states);
    // y[b][t][j] = sum_n states[t*16+b][n] * C[j][n]
    gemm512<false, true><<<grid, 256, 0, stream>>>((const void*)states, Cbf, (void*)out);
}

// Round 13
// 6202.882 us; speedup vs baseline: 1.4947x; 1.2011x over previous
//
#include <hip/hip_runtime.h>
#include <hip/hip_bf16.h>

typedef __attribute__((ext_vector_type(4))) float  fvec4;
typedef __attribute__((ext_vector_type(8))) short  svec8;    // 8 bf16 (4 VGPRs), MFMA A/B frag
typedef __attribute__((ext_vector_type(8))) unsigned short usvec8;
typedef __attribute__((ext_vector_type(4))) unsigned short usvec4;
typedef __attribute__((ext_vector_type(2))) unsigned int   uivec2;
typedef __attribute__((ext_vector_type(4))) unsigned int   uivec4;

#define MFMA16 __builtin_amdgcn_mfma_f32_16x16x32_bf16

static __device__ __forceinline__ unsigned short f2bf(float f) {
    __hip_bfloat16 h = __float2bfloat16(f);
    return __builtin_bit_cast(unsigned short, h);
}
static __device__ __forceinline__ float bf2f(unsigned short u) {
    unsigned int v = ((unsigned int)u) << 16;
    return __builtin_bit_cast(float, v);
}

// ---------------- fp32 -> bf16 convert ----------------
__global__ void cvt_kernel(const float* __restrict__ in, unsigned short* __restrict__ out, int n4) {
    int stride = gridDim.x * blockDim.x;
    for (int i = blockIdx.x * blockDim.x + threadIdx.x; i < n4; i += stride) {
        fvec4 v = ((const fvec4*)in)[i];
        usvec4 u;
        u[0] = f2bf(v[0]); u[1] = f2bf(v[1]); u[2] = f2bf(v[2]); u[3] = f2bf(v[3]);
        ((usvec4*)out)[i] = u;
    }
}

// ---------------- GEMM: out[m][n] = sum_k lhs[m][k] * rhs[n][k], K=N=512 ----------------
// (unchanged since round 1 — verified)
template<bool LHS_F32_PERM, bool OUT_PERM>
__global__ __launch_bounds__(256)
void gemm512(const void* __restrict__ lhsv, const unsigned short* __restrict__ rhs,
             void* __restrict__ outv)
{
    __shared__ __align__(16) unsigned short smA[64 * 72];
    __shared__ __align__(16) unsigned short smB[64 * 72];
    const int tid = threadIdx.x;
    const int m0 = blockIdx.x * 64;
    const int n0 = blockIdx.y * 64;
    const int w = tid >> 6, l = tid & 63;
    const int g = l >> 4, r16 = l & 15;
    const int wm = (w >> 1) * 32, wn = (w & 1) * 32;
    const int ri = tid >> 2;
    const int kseg = (tid & 3) * 16;

    fvec4 acc[2][2] = {};

    for (int k0 = 0; k0 < 512; k0 += 64) {
        if (LHS_F32_PERM) {
            const float* x = (const float*)lhsv;
            int m = m0 + ri;
            size_t base = ((size_t)(m & 15) * 4096 + (size_t)(m >> 4)) * 512 + k0 + kseg;
            usvec8 o0, o1;
            fvec4 v0 = *(const fvec4*)(x + base + 0);
            fvec4 v1 = *(const fvec4*)(x + base + 4);
            fvec4 v2 = *(const fvec4*)(x + base + 8);
            fvec4 v3 = *(const fvec4*)(x + base + 12);
            o0[0]=f2bf(v0[0]); o0[1]=f2bf(v0[1]); o0[2]=f2bf(v0[2]); o0[3]=f2bf(v0[3]);
            o0[4]=f2bf(v1[0]); o0[5]=f2bf(v1[1]); o0[6]=f2bf(v1[2]); o0[7]=f2bf(v1[3]);
            o1[0]=f2bf(v2[0]); o1[1]=f2bf(v2[1]); o1[2]=f2bf(v2[2]); o1[3]=f2bf(v2[3]);
            o1[4]=f2bf(v3[0]); o1[5]=f2bf(v3[1]); o1[6]=f2bf(v3[2]); o1[7]=f2bf(v3[3]);
            *(usvec8*)(smA + ri * 72 + kseg)     = o0;
            *(usvec8*)(smA + ri * 72 + kseg + 8) = o1;
        } else {
            const unsigned short* s = (const unsigned short*)lhsv;
            size_t base = (size_t)(m0 + ri) * 512 + k0 + kseg;
            *(usvec8*)(smA + ri * 72 + kseg)     = *(const usvec8*)(s + base);
            *(usvec8*)(smA + ri * 72 + kseg + 8) = *(const usvec8*)(s + base + 8);
        }
        {
            size_t base = (size_t)(n0 + ri) * 512 + k0 + kseg;
            *(usvec8*)(smB + ri * 72 + kseg)     = *(const usvec8*)(rhs + base);
            *(usvec8*)(smB + ri * 72 + kseg + 8) = *(const usvec8*)(rhs + base + 8);
        }
        __syncthreads();
        #pragma unroll
        for (int kt = 0; kt < 2; ++kt) {
            svec8 a0 = *(const svec8*)(smA + (wm +      r16) * 72 + 32 * kt + 8 * g);
            svec8 a1 = *(const svec8*)(smA + (wm + 16 + r16) * 72 + 32 * kt + 8 * g);
            svec8 b0 = *(const svec8*)(smB + (wn +      r16) * 72 + 32 * kt + 8 * g);
            svec8 b1 = *(const svec8*)(smB + (wn + 16 + r16) * 72 + 32 * kt + 8 * g);
            acc[0][0] = MFMA16(a0, b0, acc[0][0], 0, 0, 0);
            acc[0][1] = MFMA16(a0, b1, acc[0][1], 0, 0, 0);
            acc[1][0] = MFMA16(a1, b0, acc[1][0], 0, 0, 0);
            acc[1][1] = MFMA16(a1, b1, acc[1][1], 0, 0, 0);
        }
        __syncthreads();
    }
    #pragma unroll
    for (int mt = 0; mt < 2; ++mt)
    #pragma unroll
    for (int nt = 0; nt < 2; ++nt)
    #pragma unroll
    for (int r = 0; r < 4; ++r) {
        int m = m0 + wm + 16 * mt + 4 * g + r;
        int n = n0 + wn + 16 * nt + r16;
        float v = acc[mt][nt][r];
        if (OUT_PERM) {
            float* out = (float*)outv;
            out[((size_t)(m & 15) * 4096 + (size_t)(m >> 4)) * 512 + n] = v;
        } else {
            unsigned short* out = (unsigned short*)outv;
            out[(size_t)m * 512 + n] = f2bf(v);
        }
    }
}

// ---------------- recurrence: ONE workgroup, 8 waves (2/SIMD), PURE INTRINSICS -----------
// Round-13 = decisive experiment: r12's 8-wave geometry with ZERO inline-asm MFMA.
// All MFMAs via __builtin_amdgcn_mfma (compiler-managed hazards/waitcnts — the entire
// r11/r12 asm-at-register-cap risk class removed). No "a" constraints, no s_nop fences,
// no prefetch rotation (co-wave TLP covers ds_read latency). sched_barrier(0) per kt
// bounds the scheduler's load-hoisting so af[16][3] (192 regs) stays resident
// (r4-proven-correct combo of intrinsic MFMA + sched barriers).
// Wave w owns n_out [64w, 64w+64), FULL k; 64 MFMAs/wave/step (512/CU = same
// ~2,480-cyc floor). A-split: mt0..2 -> plain registers (48 frags = 192 regs),
// mt3 -> LDS frag-linear (16KB/wave x 8 = 128KB). LDS total 160KB exactly.
// Single barrier/step (st[2] dbuf, r7-proven). bq decoded transiently inside EP.
// cvt_pk asm kept (register-only VALU op, proven r6-r10).
// Mappings (verified rounds 2-10, absmax 0.03125):
//   A-frag: lane l -> m = l&15, k = 32kt + 8(l>>4) + e
//   B-frag: lane l -> n = l&15 (batch), k = 32kt + 8(l>>4) + e
//   C/D:    lane l -> n = l&15 (batch), m = 4(l>>4) + reg
#define RT 4096

// one kt: 2 LDS loads + 4 intrinsic MFMAs; sched_barrier bounds scheduling region
#define KTSTEP(KT) do { \
    svec8 sb = *(const svec8*)(stp + ((64 * (KT) + 16 * g) ^ swz)); \
    svec8 a3 = *(const svec8*)(ldsA + ((w * 16 + (KT)) << 9) + l * 8); \
    acc[0] = MFMA16(af[KT][0], sb, acc[0], 0, 0, 0); \
    acc[1] = MFMA16(af[KT][1], sb, acc[1], 0, 0, 0); \
    acc[2] = MFMA16(af[KT][2], sb, acc[2], 0, 0, 0); \
    acc[3] = MFMA16(a3,        sb, acc[3], 0, 0, 0); \
    __builtin_amdgcn_sched_barrier(0); \
} while (0)

// epilogue one mt: +bx (transient decode), relu, cvt_pk, ds_write st[q]
#define EP(MT) do { \
    unsigned long long _u = bq[MT]; \
    float _f0 = fmaxf(acc[MT][0] + bf2f((unsigned short)( _u        & 0xffffu)), 0.0f); \
    float _f1 = fmaxf(acc[MT][1] + bf2f((unsigned short)((_u >> 16) & 0xffffu)), 0.0f); \
    float _f2 = fmaxf(acc[MT][2] + bf2f((unsigned short)((_u >> 32) & 0xffffu)), 0.0f); \
    float _f3 = fmaxf(acc[MT][3] + bf2f((unsigned short)((_u >> 48) & 0xffffu)), 0.0f); \
    unsigned int _plo, _phi; \
    asm("v_cvt_pk_bf16_f32 %0, %1, %2" : "=v"(_plo) : "v"(_f0), "v"(_f1)); \
    asm("v_cvt_pk_bf16_f32 %0, %1, %2" : "=v"(_phi) : "v"(_f2), "v"(_f3)); \
    uivec2 _ov; _ov[0] = _plo; _ov[1] = _phi; \
    *(uivec2*)(stq + ((2 * (nbase + 16 * (MT) + 4 * g)) ^ swz)) = _ov; \
} while (0)

__global__ __launch_bounds__(512, 2)
void recur1cu_kernel(const unsigned short* __restrict__ Abf,   // [512][512] bf16, A[n][k]
                     const unsigned short* __restrict__ bx,    // [65536][512] bf16, row = t*16+b
                     unsigned short* __restrict__ states)      // [65536][512] bf16, row = t*16+b
{
    __shared__ __align__(16) unsigned short st[2][16 * 512];     // 32 KB state dbuf, XOR-swizzled
    __shared__ __align__(16) unsigned short ldsA[8 * 16 * 512];  // 128 KB: [w][kt][frag 1KB], mt3
    const int tid = threadIdx.x;
    const int w = tid >> 6, l = tid & 63;
    const int g = l >> 4, r16 = l & 15;
    const int nbase = w * 64;
    const int swz = (r16 & 7) << 4;

    // ---- stage A mt=3 into LDS, fragment-linear ----
    #pragma unroll
    for (int kt = 0; kt < 16; ++kt) {
        usvec8 v = *(const usvec8*)(Abf + (size_t)(nbase + 48 + r16) * 512 + 32 * kt + 8 * g);
        *(usvec8*)(ldsA + ((w * 16 + kt) << 9) + l * 8) = v;
    }

    // ---- preload A mt=0..2 into plain registers: 48 frags = 192 regs ----
    svec8 af[16][3];
    #pragma unroll
    for (int kt = 0; kt < 16; ++kt)
        #pragma unroll
        for (int mt = 0; mt < 3; ++mt)
            af[kt][mt] = *(const svec8*)(Abf + (size_t)(nbase + 16 * mt + r16) * 512
                                         + 32 * kt + 8 * g);

    // ---- t = 0: state0 = relu(bx[0]) -> st[0] own 64 cols ----
    {
        const unsigned short* bp = bx + (size_t)r16 * 512 + nbase + 4 * g;
        char* st0 = (char*)&st[0][0] + r16 * 1024;
        #pragma unroll
        for (int mt = 0; mt < 4; ++mt) {
            unsigned long long u = *(const unsigned long long*)(bp + 16 * mt);
            float f0 = fmaxf(bf2f((unsigned short)( u        & 0xffffu)), 0.0f);
            float f1 = fmaxf(bf2f((unsigned short)((u >> 16) & 0xffffu)), 0.0f);
            float f2 = fmaxf(bf2f((unsigned short)((u >> 32) & 0xffffu)), 0.0f);
            float f3 = fmaxf(bf2f((unsigned short)((u >> 48) & 0xffffu)), 0.0f);
            unsigned int plo, phi;
            asm("v_cvt_pk_bf16_f32 %0, %1, %2" : "=v"(plo) : "v"(f0), "v"(f1));
            asm("v_cvt_pk_bf16_f32 %0, %1, %2" : "=v"(phi) : "v"(f2), "v"(f3));
            uivec2 ov; ov[0] = plo; ov[1] = phi;
            *(uivec2*)(st0 + ((2 * (nbase + 16 * mt + 4 * g)) ^ swz)) = ov;
        }
    }
    __syncthreads();

    // export lane mapping: wave w exports state rows {2w, 2w+1}; 32 lanes x 16B per half-row
    const int erow = 2 * w + (l >> 5);
    const int eswz = (erow & 7) << 4;
    const int ecol = (l & 31) * 16;

    #pragma unroll 1
    for (int t = 1; t < RT; ++t) {
        const char* stbase_p = (const char*)&st[(t - 1) & 1][0];
        char* stq = (char*)&st[t & 1][0] + r16 * 1024;

        // A) coalesced export of state_{t-1}; store drain overlaps MFMA region
        {
            const char* sp = stbase_p + erow * 1024;
            char* gp = (char*)states + ((size_t)(t - 1) * 16 + erow) * 1024 + ecol;
            #pragma unroll
            for (int jj = 0; jj < 2; ++jj) {
                uivec4 v = *(const uivec4*)(sp + ((ecol + 512 * jj) ^ eswz));
                *(uivec4*)(gp + 512 * jj) = v;
            }
        }

        // B) bx[t] loads (decoded transiently inside EP)
        unsigned long long bq[4];
        {
            const unsigned short* bp = bx + ((size_t)t * 16 + r16) * 512 + nbase + 4 * g;
            #pragma unroll
            for (int mt = 0; mt < 4; ++mt)
                bq[mt] = *(const unsigned long long*)(bp + 16 * mt);
        }

        // C) MFMA train: 16 kt x 4 intrinsic MFMAs, reads st[p]
        fvec4 acc[4];
        #pragma unroll
        for (int mt = 0; mt < 4; ++mt) acc[mt] = fvec4{0.f, 0.f, 0.f, 0.f};

        const char* stp = stbase_p + r16 * 1024;
        KTSTEP(0);  KTSTEP(1);  KTSTEP(2);  KTSTEP(3);
        KTSTEP(4);  KTSTEP(5);  KTSTEP(6);  KTSTEP(7);
        KTSTEP(8);  KTSTEP(9);  KTSTEP(10); KTSTEP(11);
        KTSTEP(12); KTSTEP(13); KTSTEP(14); KTSTEP(15);

        // D) epilogue: + bx, relu, cvt_pk, write st[q] own cols
        EP(0); EP(1); EP(2); EP(3);

        __syncthreads();   // st[q] complete; st[p] free for overwrite next iteration
    }

    // ---- final export: state_{RT-1} from st[(RT-1)&1] ----
    {
        const char* sp = (const char*)&st[(RT - 1) & 1][0] + erow * 1024;
        char* gp = (char*)states + ((size_t)(RT - 1) * 16 + erow) * 1024 + ecol;
        #pragma unroll
        for (int jj = 0; jj < 2; ++jj) {
            uivec4 v = *(const uivec4*)(sp + ((ecol + 512 * jj) ^ eswz));
            *(uivec4*)(gp + 512 * jj) = v;
        }
    }
}

extern "C" void kernel_launch(void* const* d_in, const int* in_sizes, int n_in,
                              void* d_out, int out_size, void* d_ws, size_t ws_size,
                              hipStream_t stream) {
    const float* x = (const float*)d_in[0];   // [16][4096][512]
    const float* A = (const float*)d_in[1];   // [512][512]
    const float* B = (const float*)d_in[2];   // [512][512]
    const float* C = (const float*)d_in[3];   // [512][512]
    float* out = (float*)d_out;               // [16][4096][512]

    char* ws = (char*)d_ws;
    unsigned short* Abf = (unsigned short*)(ws + 0);                          // 512KB
    unsigned short* Bbf = (unsigned short*)(ws + (size_t)(1 << 19));          // 512KB
    unsigned short* Cbf = (unsigned short*)(ws + (size_t)(2 << 19));          // 512KB
    unsigned short* bx  = (unsigned short*)(ws + (size_t)(4 << 19));          // 64MB: [65536][512] bf16
    unsigned short* states = (unsigned short*)(ws + (size_t)(4 << 19) + ((size_t)1 << 26)); // 64MB

    cvt_kernel<<<64, 256, 0, stream>>>(A, Abf, 512 * 512 / 4);
    cvt_kernel<<<64, 256, 0, stream>>>(B, Bbf, 512 * 512 / 4);
    cvt_kernel<<<64, 256, 0, stream>>>(C, Cbf, 512 * 512 / 4);

    dim3 grid(1024, 8);
    // bx[t*16+b][n] = sum_d x[b][t][d] * B[n][d]
    gemm512<true, false><<<grid, 256, 0, stream>>>((const void*)x, Bbf, (void*)bx);
    // sequential recurrence on one CU, 8 waves, states[t*16+b][n]
    recur1cu_kernel<<<1, 512, 0, stream>>>(Abf, bx, states);
    // y[b][t][j] = sum_n states[t*16+b][n] * C[j][n]
    gemm512<false, true><<<grid, 256, 0, stream>>>((const void*)states, Cbf, (void*)out);
}